// Round 4
// baseline (247.535 us; speedup 1.0000x reference)
//
#include <hip/hip_runtime.h>
#include <stdint.h>

#define BB 8
#define NN 50000
#define SCORE_THR 0.99f
#define NMS_THR 0.5f
#define MAX_DET 100
#define K_PRE 1024
#define CAP 2048
#define KEEP_CAP 128
#define CNT_STRIDE 64   // ints => 256 B per counter, one counter per cache line

typedef unsigned long long u64;
typedef unsigned int u32;
typedef __attribute__((ext_vector_type(2))) unsigned long long u64x2;

// ws layout:
//   int cand_cnt[64*CNT_STRIDE]   @ 0           (16 KB, padded counters)
//   int kept_cnt[64]              @ 16384
//   u64 cand_keys[64*CAP]         @ 16896
//   u64 kept_keys[64*KEEP_CAP]    @ 16896 + 64*CAP*8

__global__ void k_init(int* __restrict__ cnts) {
    for (int i = threadIdx.x; i < 64 * CNT_STRIDE + 64; i += 256) cnts[i] = 0;
}

__global__ __launch_bounds__(256) void k_filter(const float* __restrict__ cls,
                                                int* __restrict__ cand_cnt,
                                                u64* __restrict__ cand_keys) {
    __shared__ int wcnt[8][4];
    __shared__ int woff[8][4];
    __shared__ int cbase[8];
    int b = blockIdx.y;
    int tid = threadIdx.x;
    int lane = tid & 63, w = tid >> 6;
    int n = blockIdx.x * 256 + tid;
    bool vn = n < NN;
    float s[8];
    if (vn) {
        const float4* p = (const float4*)(cls + ((size_t)b * NN + n) * 8);
        float4 a = p[0], b2 = p[1];
        s[0] = a.x; s[1] = a.y; s[2] = a.z; s[3] = a.w;
        s[4] = b2.x; s[5] = b2.y; s[6] = b2.z; s[7] = b2.w;
    } else {
        #pragma unroll
        for (int c = 0; c < 8; ++c) s[c] = 0.f;
    }
    u64 bal[8];
    #pragma unroll
    for (int c = 0; c < 8; ++c) {
        bool pred = vn && (s[c] > SCORE_THR);
        bal[c] = __ballot(pred);
        if (lane == 0) wcnt[c][w] = (int)__popcll(bal[c]);
    }
    __syncthreads();
    if (tid < 8) {
        int c = tid, acc = 0;
        #pragma unroll
        for (int ww = 0; ww < 4; ++ww) { woff[c][ww] = acc; acc += wcnt[c][ww]; }
        cbase[c] = acc ? atomicAdd(&cand_cnt[(b * 8 + c) * CNT_STRIDE], acc) : 0;
    }
    __syncthreads();
    #pragma unroll
    for (int c = 0; c < 8; ++c) {
        if (vn && (s[c] > SCORE_THR)) {
            int slot = cbase[c] + woff[c][w] + (int)__popcll(bal[c] & ((1ull << lane) - 1ull));
            if (slot < CAP)
                cand_keys[(size_t)(b * 8 + c) * CAP + slot] =
                    ((u64)__float_as_uint(s[c]) << 32) | (u32)(~(u32)n);
        }
    }
}

__global__ __launch_bounds__(256) void k_nms(const float* __restrict__ boxes,
                                             const int* __restrict__ cand_cnt,
                                             const u64* __restrict__ cand_keys,
                                             int* __restrict__ kept_cnt,
                                             u64* __restrict__ kept_keys) {
    __shared__ __align__(16) u64 sk_in[CAP];
    __shared__ u64 sk[K_PRE];
    __shared__ float bx1[K_PRE], by1[K_PRE], bx2[K_PRE], by2[K_PRE], bar[K_PRE];
    __shared__ int keep[K_PRE];
    __shared__ int sup[K_PRE];
    __shared__ u64 tmask[64];
    __shared__ u64 kbs;
    __shared__ int wsum[16];
    __shared__ int wpre[17];
    int tid = threadIdx.x;
    int bc = blockIdx.x;
    int c = bc & 7;
    int b = bc >> 3;
    int lane = tid & 63, w = tid >> 6;
    int cnt = cand_cnt[bc * CNT_STRIDE];
    if (cnt > CAP) cnt = CAP;
    int cnt2 = (cnt + 1) & ~1;          // pad to even for paired reads
    for (int i = tid; i < cnt2; i += 256)
        sk_in[i] = (i < cnt) ? cand_keys[(size_t)bc * CAP + i] : 0ull;
    __syncthreads();
    // ---- rank sort: pos[i] = #{j : key[j] > key[i]}  (keys globally distinct) ----
    int nv = cnt2 >> 1;
    const u64x2* skv = (const u64x2*)sk_in;
    for (int g = 0; g < cnt; g += 1024) {
        int i0 = g + tid, i1 = i0 + 256, i2 = i0 + 512, i3 = i0 + 768;
        u64 k0 = (i0 < cnt) ? sk_in[i0] : 0ull;
        u64 k1 = (i1 < cnt) ? sk_in[i1] : 0ull;
        u64 k2 = (i2 < cnt) ? sk_in[i2] : 0ull;
        u64 k3 = (i3 < cnt) ? sk_in[i3] : 0ull;
        int r0 = 0, r1 = 0, r2 = 0, r3 = 0;
        #pragma unroll 4
        for (int jv = 0; jv < nv; ++jv) {
            u64x2 kk = skv[jv];
            r0 += (kk.x > k0); r0 += (kk.y > k0);
            r1 += (kk.x > k1); r1 += (kk.y > k1);
            r2 += (kk.x > k2); r2 += (kk.y > k2);
            r3 += (kk.x > k3); r3 += (kk.y > k3);
        }
        if (i0 < cnt && r0 < K_PRE) sk[r0] = k0;
        if (i1 < cnt && r1 < K_PRE) sk[r1] = k1;
        if (i2 < cnt && r2 < K_PRE) sk[r2] = k2;
        if (i3 < cnt && r3 < K_PRE) sk[r3] = k3;
    }
    __syncthreads();
    int n_cand = cnt < K_PRE ? cnt : K_PRE;
    // ---- gather boxes (sorted order) + init keep/sup ----
    for (int i = tid; i < K_PRE; i += 256) {
        keep[i] = 0; sup[i] = 0;
        float x1 = 0.f, y1 = 0.f, x2 = 0.f, y2 = 0.f;
        if (i < n_cand) {
            u32 n = ~(u32)sk[i];
            const float4 b4 = *(const float4*)(boxes + ((size_t)b * NN + n) * 4);
            x1 = b4.x; y1 = b4.y; x2 = b4.z; y2 = b4.w;
        }
        bx1[i] = x1; by1[i] = y1; bx2[i] = x2; by2[i] = y2;
        bar[i] = (x2 - x1) * (y2 - y1);
    }
    __syncthreads();
    // ---- tiled greedy NMS ----
    int ntiles = (n_cand + 63) >> 6;
    for (int t = 0; t < ntiles; ++t) {
        int s0 = t << 6;
        // 1) in-tile 64x64 IoU bit matrix, pure registers + shuffles
        {
            float cx1 = bx1[s0 + lane], cy1 = by1[s0 + lane];
            float cx2 = bx2[s0 + lane], cy2 = by2[s0 + lane];
            float ca  = bar[s0 + lane];
            #pragma unroll
            for (int r = 0; r < 16; ++r) {
                int jj = (w << 4) | r;
                float rx1 = __shfl(cx1, jj);
                float ry1 = __shfl(cy1, jj);
                float rx2 = __shfl(cx2, jj);
                float ry2 = __shfl(cy2, jj);
                float ra  = __shfl(ca, jj);
                float iw = fminf(rx2, cx2) - fmaxf(rx1, cx1);
                float ih = fminf(ry2, cy2) - fmaxf(ry1, cy1);
                iw = fmaxf(iw, 0.f); ih = fmaxf(ih, 0.f);
                float inter = iw * ih;
                float iou = inter / (ra + ca - inter);
                bool p = (lane < jj) && (s0 + jj < n_cand) && (iou > NMS_THR);
                u64 m = __ballot(p);
                if (lane == 0) tmask[jj] = m;
            }
        }
        __syncthreads();
        // 2) wave-0 in-register greedy over the tile (alive-mask trick)
        if (w == 0) {
            int nmax = n_cand - s0; if (nmax > 64) nmax = 64;
            u64 rowmask = tmask[lane];
            int el = (lane < nmax) && (sup[s0 + lane] == 0);
            u64 alive = __ballot(el != 0);
            u64 kb = 0;
            while (alive) {
                int j = __ffsll(alive) - 1;
                kb |= (1ull << j);
                u64 colj = __ballot(((rowmask >> j) & 1ull) != 0);
                alive &= ~(colj | (1ull << j));
            }
            keep[s0 + lane] = (int)((kb >> lane) & 1ull);
            if (lane == 0) kbs = kb;
        }
        __syncthreads();
        // 3) parallel forward suppression: later candidates vs kept-in-tile
        {
            u64 kb = kbs;
            if (kb) {
                for (int j2 = s0 + 64 + tid; j2 < n_cand; j2 += 256) {
                    if (sup[j2]) continue;
                    float x1 = bx1[j2], y1 = by1[j2], x2 = bx2[j2], y2 = by2[j2], aj = bar[j2];
                    u64 m = kb;
                    int supped = 0;
                    while (m) {
                        int k = __ffsll(m) - 1; m &= m - 1ull;
                        int i = s0 + k;
                        float iw = fminf(x2, bx2[i]) - fmaxf(x1, bx1[i]);
                        float ih = fminf(y2, by2[i]) - fmaxf(y1, by1[i]);
                        iw = fmaxf(iw, 0.f); ih = fmaxf(ih, 0.f);
                        float inter = iw * ih;
                        float iou = inter / (aj + bar[i] - inter);
                        if (iou > NMS_THR) { supped = 1; break; }
                    }
                    if (supped) sup[j2] = 1;
                }
            }
        }
        __syncthreads();
    }
    // ---- ordered compaction of kept candidates (first KEEP_CAP per class) ----
    bool kpq[4]; u64 balq[4];
    #pragma unroll
    for (int q = 0; q < 4; ++q) {
        int i = q * 256 + tid;
        kpq[q] = (i < n_cand) && keep[i];
        balq[q] = __ballot(kpq[q]);
        if (lane == 0) wsum[q * 4 + w] = (int)__popcll(balq[q]);
    }
    __syncthreads();
    if (tid == 0) {
        int acc = 0;
        for (int i = 0; i < 16; ++i) { wpre[i] = acc; acc += wsum[i]; }
        wpre[16] = acc;
        kept_cnt[bc] = acc < KEEP_CAP ? acc : KEEP_CAP;
    }
    __syncthreads();
    #pragma unroll
    for (int q = 0; q < 4; ++q) {
        if (kpq[q]) {
            int i = q * 256 + tid;
            int rank = wpre[q * 4 + w] + (int)__popcll(balq[q] & ((1ull << lane) - 1ull));
            if (rank < KEEP_CAP) {
                u64 key = sk[i];
                u32 sb = (u32)(key >> 32);
                u32 n = (~(u32)key) & 0x1FFFFu;
                int pos = c * K_PRE + i;   // position in the reference's [c*K_PRE] sc array
                kept_keys[(size_t)bc * KEEP_CAP + rank] =
                    ((u64)sb << 30) | ((u64)(8191 - pos) << 17) | (u64)n;
            }
        }
    }
}

__global__ __launch_bounds__(1024) void k_final(const float* __restrict__ boxes,
                                                const float* __restrict__ rot,
                                                const float* __restrict__ trans,
                                                const int* __restrict__ kept_cnt,
                                                const u64* __restrict__ kept_keys,
                                                float* __restrict__ out) {
    __shared__ u64 fk[1024];      // 8 strictly-descending runs of 128 (0-padded)
    __shared__ int scnt[8];
    int tid = threadIdx.x;
    int b = blockIdx.x;
    int c = tid >> 7, i = tid & 127;
    if (tid < 8) scnt[tid] = kept_cnt[b * 8 + tid];
    int cc = kept_cnt[b * 8 + c];
    u64 key = (i < cc) ? kept_keys[(size_t)(b * 8 + c) * KEEP_CAP + i] : 0ull;
    fk[tid] = key;
    __syncthreads();
    int total = 0;
    #pragma unroll
    for (int r = 0; r < 8; ++r) total += scnt[r];
    if (i < cc) {
        // global rank = own index + countGreater in the 7 other runs (binary search)
        int rank = i;
        #pragma unroll
        for (int r = 0; r < 8; ++r) {
            if (r == c) continue;
            int basei = r << 7;
            int lo;
            if (fk[basei + 127] > key) lo = 128;
            else {
                lo = 0;
                #pragma unroll
                for (int s = 64; s > 0; s >>= 1)
                    if (fk[basei + lo + s - 1] > key) lo += s;
            }
            rank += lo;
        }
        if (rank < MAX_DET) {
            u32 n = (u32)(key & 0x1FFFFu);
            int pos = 8191 - (int)((key >> 17) & 0x1FFFu);
            int cls = pos >> 10;
            float osc = __uint_as_float((u32)(key >> 30));
            const float* bp = boxes + ((size_t)b * NN + n) * 4;
            const float* rp = rot + ((size_t)b * NN + n) * 3;
            const float* tp = trans + ((size_t)b * NN + n) * 3;
            int base = b * MAX_DET + rank;
            out[base * 4 + 0] = bp[0];
            out[base * 4 + 1] = bp[1];
            out[base * 4 + 2] = bp[2];
            out[base * 4 + 3] = bp[3];
            out[BB * MAX_DET * 4 + base] = osc;
            out[BB * MAX_DET * 5 + base] = (float)cls;
            float* ro = out + BB * MAX_DET * 6;
            ro[base * 3 + 0] = rp[0];
            ro[base * 3 + 1] = rp[1];
            ro[base * 3 + 2] = rp[2];
            float* to = out + BB * MAX_DET * 6 + BB * MAX_DET * 3;
            to[base * 3 + 0] = tp[0];
            to[base * 3 + 1] = tp[1];
            to[base * 3 + 2] = tp[2];
        }
    }
    if (tid < MAX_DET && tid >= total) {   // rows [total, 100) get the -1 fill
        int base = b * MAX_DET + tid;
        out[base * 4 + 0] = -1.f;
        out[base * 4 + 1] = -1.f;
        out[base * 4 + 2] = -1.f;
        out[base * 4 + 3] = -1.f;
        out[BB * MAX_DET * 4 + base] = -1.f;
        out[BB * MAX_DET * 5 + base] = -1.f;
        float* ro = out + BB * MAX_DET * 6;
        ro[base * 3 + 0] = -1.f;
        ro[base * 3 + 1] = -1.f;
        ro[base * 3 + 2] = -1.f;
        float* to = out + BB * MAX_DET * 6 + BB * MAX_DET * 3;
        to[base * 3 + 0] = -1.f;
        to[base * 3 + 1] = -1.f;
        to[base * 3 + 2] = -1.f;
    }
}

extern "C" void kernel_launch(void* const* d_in, const int* in_sizes, int n_in,
                              void* d_out, int out_size, void* d_ws, size_t ws_size,
                              hipStream_t stream) {
    const float* boxes = (const float*)d_in[0];
    const float* cls   = (const float*)d_in[1];
    const float* rot   = (const float*)d_in[2];
    const float* trans = (const float*)d_in[3];
    int* cand_cnt = (int*)d_ws;
    int* kept_cnt = cand_cnt + 64 * CNT_STRIDE;
    u64* cand_keys = (u64*)((char*)d_ws + 16896);
    u64* kept_keys = (u64*)((char*)d_ws + 16896 + (size_t)64 * CAP * 8);
    float* out = (float*)d_out;

    hipLaunchKernelGGL(k_init, dim3(1), dim3(256), 0, stream, cand_cnt);
    hipLaunchKernelGGL(k_filter, dim3((NN + 255) / 256, BB), dim3(256), 0, stream,
                       cls, cand_cnt, cand_keys);
    hipLaunchKernelGGL(k_nms, dim3(64), dim3(256), 0, stream,
                       boxes, cand_cnt, cand_keys, kept_cnt, kept_keys);
    hipLaunchKernelGGL(k_final, dim3(BB), dim3(1024), 0, stream,
                       boxes, rot, trans, kept_cnt, kept_keys, out);
}

// Round 5
// 138.998 us; speedup vs baseline: 1.7809x; 1.7809x over previous
//
#include <hip/hip_runtime.h>
#include <stdint.h>

#define BB 8
#define NN 50000
#define SCORE_THR 0.99f
#define NMS_THR 0.5f
#define MAX_DET 100
#define K_PRE 1024
#define CAP 2048
#define KEEP_CAP 128
#define CNT_STRIDE 64      // ints => 256 B per counter
#define T_MAX 16           // K_PRE / 64
#define NPAIR 136          // T_MAX*(T_MAX+1)/2
#define TRI_WORDS 8704     // 64 * NPAIR  (u64 words per (b,c))

typedef unsigned long long u64;
typedef unsigned int u32;
typedef __attribute__((ext_vector_type(2))) unsigned long long u64x2;

// ws layout (bytes):
//   int  cand_cnt[64*CNT_STRIDE]      @ 0          (16384)
//   int  kept_cnt[64]                 @ 16384
//   u64  cand_keys[64*CAP]            @ 16896      (1 MB)
//   u64  kept_keys[64*KEEP_CAP]       @ 1065472    (64 KB)
//   u64  sk_g[64*K_PRE]              @ 1131008    (512 KB)  sorted keys
//   float4 box4[64*K_PRE]            @ 1655296    (1 MB)    sorted boxes
//   u64  rowmask[64*TRI_WORDS]       @ 2703872    (~4.25 MB) triangular bit-matrix

__global__ void k_init(int* __restrict__ cnts) {
    for (int i = threadIdx.x; i < 64 * CNT_STRIDE + 64; i += 256) cnts[i] = 0;
}

__global__ __launch_bounds__(256) void k_filter(const float* __restrict__ cls,
                                                int* __restrict__ cand_cnt,
                                                u64* __restrict__ cand_keys) {
    __shared__ int wcnt[8][4];
    __shared__ int woff[8][4];
    __shared__ int cbase[8];
    int b = blockIdx.y;
    int tid = threadIdx.x;
    int lane = tid & 63, w = tid >> 6;
    int n = blockIdx.x * 256 + tid;
    bool vn = n < NN;
    float s[8];
    if (vn) {
        const float4* p = (const float4*)(cls + ((size_t)b * NN + n) * 8);
        float4 a = p[0], b2 = p[1];
        s[0] = a.x; s[1] = a.y; s[2] = a.z; s[3] = a.w;
        s[4] = b2.x; s[5] = b2.y; s[6] = b2.z; s[7] = b2.w;
    } else {
        #pragma unroll
        for (int c = 0; c < 8; ++c) s[c] = 0.f;
    }
    u64 bal[8];
    #pragma unroll
    for (int c = 0; c < 8; ++c) {
        bool pred = vn && (s[c] > SCORE_THR);
        bal[c] = __ballot(pred);
        if (lane == 0) wcnt[c][w] = (int)__popcll(bal[c]);
    }
    __syncthreads();
    if (tid < 8) {
        int c = tid, acc = 0;
        #pragma unroll
        for (int ww = 0; ww < 4; ++ww) { woff[c][ww] = acc; acc += wcnt[c][ww]; }
        cbase[c] = acc ? atomicAdd(&cand_cnt[(b * 8 + c) * CNT_STRIDE], acc) : 0;
    }
    __syncthreads();
    #pragma unroll
    for (int c = 0; c < 8; ++c) {
        if (vn && (s[c] > SCORE_THR)) {
            int slot = cbase[c] + woff[c][w] + (int)__popcll(bal[c] & ((1ull << lane) - 1ull));
            if (slot < CAP)
                cand_keys[(size_t)(b * 8 + c) * CAP + slot] =
                    ((u64)__float_as_uint(s[c]) << 32) | (u32)(~(u32)n);
        }
    }
}

// rank-sort candidates of one (b,c); emit sorted keys + gathered boxes to global
__global__ __launch_bounds__(1024) void k_sort(const float* __restrict__ boxes,
                                               const int* __restrict__ cand_cnt,
                                               const u64* __restrict__ cand_keys,
                                               u64* __restrict__ sk_g,
                                               float4* __restrict__ box4) {
    __shared__ __align__(16) u64 sk_in[CAP];
    int tid = threadIdx.x;
    int bc = blockIdx.x;
    int b = bc >> 3;
    int cnt = cand_cnt[bc * CNT_STRIDE];
    if (cnt > CAP) cnt = CAP;
    int cnt2 = (cnt + 1) & ~1;
    for (int i = tid; i < cnt2; i += 1024)
        sk_in[i] = (i < cnt) ? cand_keys[(size_t)bc * CAP + i] : 0ull;
    __syncthreads();
    int nv = cnt2 >> 1;
    const u64x2* skv = (const u64x2*)sk_in;
    for (int g = 0; g < cnt; g += 1024) {
        int i0 = g + tid;
        u64 k0 = (i0 < cnt) ? sk_in[i0] : 0ull;
        int r0 = 0;
        #pragma unroll 4
        for (int jv = 0; jv < nv; ++jv) {
            u64x2 kk = skv[jv];
            r0 += (kk.x > k0); r0 += (kk.y > k0);
        }
        if (i0 < cnt && r0 < K_PRE) {
            sk_g[(size_t)bc * K_PRE + r0] = k0;
            u32 n = ~(u32)k0;
            box4[(size_t)bc * K_PRE + r0] =
                *(const float4*)(boxes + ((size_t)b * NN + n) * 4);
        }
    }
}

// triangular IoU bit matrix: block (pair p, bc); word (row i, tile tj) over cols j<i
__global__ __launch_bounds__(256) void k_iou(const int* __restrict__ cand_cnt,
                                             const float4* __restrict__ box4,
                                             u64* __restrict__ rowmask) {
    int bc = blockIdx.y;
    int p = blockIdx.x;
    int cnt = cand_cnt[bc * CNT_STRIDE];
    int n_cand = cnt < K_PRE ? cnt : K_PRE;
    int ntiles = (n_cand + 63) >> 6;
    int ti = 0, acc = 0;
    while (acc + ti + 1 <= p) { acc += ti + 1; ++ti; }
    int tj = p - acc;
    if (ti >= ntiles) return;
    const float4* bx = box4 + (size_t)bc * K_PRE;
    __shared__ float4 srb[64];
    int tid = threadIdx.x;
    int lane = tid & 63, w = tid >> 6;
    if (tid < 64) srb[tid] = bx[ti * 64 + tid];
    __syncthreads();
    int cg = tj * 64 + lane;
    float4 cb = bx[cg];
    float ca = (cb.z - cb.x) * (cb.w - cb.y);
    u64* out = rowmask + (size_t)bc * TRI_WORDS + 64 * (ti * (ti + 1) / 2) + tj;
    #pragma unroll
    for (int r16 = 0; r16 < 16; ++r16) {
        int r = (w << 4) | r16;
        float4 rb = srb[r];
        float ra = (rb.z - rb.x) * (rb.w - rb.y);
        float iw = fminf(rb.z, cb.z) - fmaxf(rb.x, cb.x);
        float ih = fminf(rb.w, cb.w) - fmaxf(rb.y, cb.y);
        iw = fmaxf(iw, 0.f); ih = fmaxf(ih, 0.f);
        float inter = iw * ih;
        float iou = inter / (ra + ca - inter);
        int rg = ti * 64 + r;
        bool pr = (rg < n_cand) && (cg < n_cand) && ((ti != tj) || (lane < r)) &&
                  (iou > NMS_THR);
        u64 m = __ballot(pr);
        if (lane == 0) out[(size_t)r * (ti + 1)] = m;
    }
}

// one wave per (b,c): greedy scan over precomputed bit matrix, emit kept keys
__global__ __launch_bounds__(64) void k_greedy(const int* __restrict__ cand_cnt,
                                               const u64* __restrict__ sk_g,
                                               const u64* __restrict__ rowmask,
                                               int* __restrict__ kept_cnt,
                                               u64* __restrict__ kept_keys) {
    int lane = threadIdx.x;
    int bc = blockIdx.x;
    int c = bc & 7;
    int cnt = cand_cnt[bc * CNT_STRIDE];
    int n_cand = cnt < K_PRE ? cnt : K_PRE;
    int ntiles = (n_cand + 63) >> 6;
    const u64* tri = rowmask + (size_t)bc * TRI_WORDS;
    u64 kept_w[T_MAX];
    #pragma unroll
    for (int t = 0; t < T_MAX; ++t) kept_w[t] = 0ull;
    for (int t = 0; t < ntiles; ++t) {
        int g = t * 64 + lane;
        const u64* base = tri + 64 * (t * (t + 1) / 2) + (size_t)lane * (t + 1);
        u64 supbits = 0;
        #pragma unroll
        for (int w = 0; w < T_MAX - 1; ++w)
            if (w < t) supbits |= base[w] & kept_w[w];
        u64 rowm = base[t];
        bool el = (g < n_cand) && (supbits == 0ull);
        u64 alive = __ballot(el);
        u64 kb = 0;
        while (alive) {
            int j = __ffsll(alive) - 1;
            kb |= (1ull << j);
            u64 colj = __ballot(((rowm >> j) & 1ull) != 0);
            alive &= ~(colj | (1ull << j));
        }
        #pragma unroll
        for (int w = 0; w < T_MAX; ++w)
            if (w == t) kept_w[w] = kb;
    }
    // compaction: rank kept candidates in sorted order, write kept_keys
    u64 lmask = (1ull << lane) - 1ull;
    int pre = 0;
    #pragma unroll
    for (int t = 0; t < T_MAX; ++t) {
        if (t < ntiles) {
            u64 kb = kept_w[t];
            if ((kb >> lane) & 1ull) {
                int rank = pre + (int)__popcll(kb & lmask);
                if (rank < KEEP_CAP) {
                    int i = t * 64 + lane;
                    u64 key = sk_g[(size_t)bc * K_PRE + i];
                    u32 sb = (u32)(key >> 32);
                    u32 n = (~(u32)key) & 0x1FFFFu;
                    int pos = c * K_PRE + i;
                    kept_keys[(size_t)bc * KEEP_CAP + rank] =
                        ((u64)sb << 30) | ((u64)(8191 - pos) << 17) | (u64)n;
                }
            }
            pre += (int)__popcll(kb);
        }
    }
    if (lane == 0) kept_cnt[bc] = pre < KEEP_CAP ? pre : KEEP_CAP;
}

__global__ __launch_bounds__(1024) void k_final(const float* __restrict__ boxes,
                                                const float* __restrict__ rot,
                                                const float* __restrict__ trans,
                                                const int* __restrict__ kept_cnt,
                                                const u64* __restrict__ kept_keys,
                                                float* __restrict__ out) {
    __shared__ u64 fk[1024];      // 8 strictly-descending runs of 128 (0-padded)
    __shared__ int scnt[8];
    int tid = threadIdx.x;
    int b = blockIdx.x;
    int c = tid >> 7, i = tid & 127;
    if (tid < 8) scnt[tid] = kept_cnt[b * 8 + tid];
    int cc = kept_cnt[b * 8 + c];
    u64 key = (i < cc) ? kept_keys[(size_t)(b * 8 + c) * KEEP_CAP + i] : 0ull;
    fk[tid] = key;
    __syncthreads();
    int total = 0;
    #pragma unroll
    for (int r = 0; r < 8; ++r) total += scnt[r];
    if (i < cc) {
        int rank = i;
        #pragma unroll
        for (int r = 0; r < 8; ++r) {
            if (r == c) continue;
            int basei = r << 7;
            int lo;
            if (fk[basei + 127] > key) lo = 128;
            else {
                lo = 0;
                #pragma unroll
                for (int s = 64; s > 0; s >>= 1)
                    if (fk[basei + lo + s - 1] > key) lo += s;
            }
            rank += lo;
        }
        if (rank < MAX_DET) {
            u32 n = (u32)(key & 0x1FFFFu);
            int pos = 8191 - (int)((key >> 17) & 0x1FFFu);
            int cls = pos >> 10;
            float osc = __uint_as_float((u32)(key >> 30));
            const float* bp = boxes + ((size_t)b * NN + n) * 4;
            const float* rp = rot + ((size_t)b * NN + n) * 3;
            const float* tp = trans + ((size_t)b * NN + n) * 3;
            int base = b * MAX_DET + rank;
            out[base * 4 + 0] = bp[0];
            out[base * 4 + 1] = bp[1];
            out[base * 4 + 2] = bp[2];
            out[base * 4 + 3] = bp[3];
            out[BB * MAX_DET * 4 + base] = osc;
            out[BB * MAX_DET * 5 + base] = (float)cls;
            float* ro = out + BB * MAX_DET * 6;
            ro[base * 3 + 0] = rp[0];
            ro[base * 3 + 1] = rp[1];
            ro[base * 3 + 2] = rp[2];
            float* to = out + BB * MAX_DET * 6 + BB * MAX_DET * 3;
            to[base * 3 + 0] = tp[0];
            to[base * 3 + 1] = tp[1];
            to[base * 3 + 2] = tp[2];
        }
    }
    if (tid < MAX_DET && tid >= total) {
        int base = b * MAX_DET + tid;
        out[base * 4 + 0] = -1.f;
        out[base * 4 + 1] = -1.f;
        out[base * 4 + 2] = -1.f;
        out[base * 4 + 3] = -1.f;
        out[BB * MAX_DET * 4 + base] = -1.f;
        out[BB * MAX_DET * 5 + base] = -1.f;
        float* ro = out + BB * MAX_DET * 6;
        ro[base * 3 + 0] = -1.f;
        ro[base * 3 + 1] = -1.f;
        ro[base * 3 + 2] = -1.f;
        float* to = out + BB * MAX_DET * 6 + BB * MAX_DET * 3;
        to[base * 3 + 0] = -1.f;
        to[base * 3 + 1] = -1.f;
        to[base * 3 + 2] = -1.f;
    }
}

extern "C" void kernel_launch(void* const* d_in, const int* in_sizes, int n_in,
                              void* d_out, int out_size, void* d_ws, size_t ws_size,
                              hipStream_t stream) {
    const float* boxes = (const float*)d_in[0];
    const float* cls   = (const float*)d_in[1];
    const float* rot   = (const float*)d_in[2];
    const float* trans = (const float*)d_in[3];
    char* ws = (char*)d_ws;
    int* cand_cnt  = (int*)ws;
    int* kept_cnt  = (int*)(ws + 16384);
    u64* cand_keys = (u64*)(ws + 16896);
    u64* kept_keys = (u64*)(ws + 1065472);
    u64* sk_g      = (u64*)(ws + 1131008);
    float4* box4   = (float4*)(ws + 1655296);
    u64* rowmask   = (u64*)(ws + 2703872);
    float* out = (float*)d_out;

    hipLaunchKernelGGL(k_init, dim3(1), dim3(256), 0, stream, cand_cnt);
    hipLaunchKernelGGL(k_filter, dim3((NN + 255) / 256, BB), dim3(256), 0, stream,
                       cls, cand_cnt, cand_keys);
    hipLaunchKernelGGL(k_sort, dim3(64), dim3(1024), 0, stream,
                       boxes, cand_cnt, cand_keys, sk_g, box4);
    hipLaunchKernelGGL(k_iou, dim3(NPAIR, 64), dim3(256), 0, stream,
                       cand_cnt, box4, rowmask);
    hipLaunchKernelGGL(k_greedy, dim3(64), dim3(64), 0, stream,
                       cand_cnt, sk_g, rowmask, kept_cnt, kept_keys);
    hipLaunchKernelGGL(k_final, dim3(BB), dim3(1024), 0, stream,
                       boxes, rot, trans, kept_cnt, kept_keys, out);
}